// Round 1
// 693.592 us; speedup vs baseline: 1.2022x; 1.2022x over previous
//
#include <hip/hip_runtime.h>
#include <math.h>
#include <cstdint>

// Problem constants (from reference)
#define Bb 4
#define Ss 2048
#define Hh 1024
#define Ee 8
#define Kk 512
#define Ff 4096

typedef short bf16x8 __attribute__((ext_vector_type(8)));       // 8 bf16 in 4 VGPRs
typedef unsigned short u16x8 __attribute__((ext_vector_type(8)));
typedef float f32x4 __attribute__((ext_vector_type(4)));

// fp32 -> bf16 round-to-nearest-even (bit form)
__device__ __forceinline__ unsigned short f2bf(float f) {
    unsigned int u = __float_as_uint(f);
    u = (u + 0x7FFFu + ((u >> 16) & 1u)) >> 16;
    return (unsigned short)u;
}

// async 16B global->LDS copy (global_load_lds_dwordx4). LDS dest is
// wave-uniform base + lane*16 (m104/m108). Source address is per-lane.
__device__ __forceinline__ void async_copy16(const void* gsrc, void* ldst) {
    auto* g = reinterpret_cast<__attribute__((address_space(1))) void*>(
        reinterpret_cast<uintptr_t>(gsrc));
    auto* l = reinterpret_cast<__attribute__((address_space(3))) void*>(
        (unsigned int)reinterpret_cast<uintptr_t>(ldst));
    __builtin_amdgcn_global_load_lds(g, l, 16, 0, 0);
}

// exact tanh-gelu via fast exp (no libcall)
__device__ __forceinline__ float gelu(float v) {
    float uu = 0.7978845608028654f * (v + 0.044715f * v * v * v);
    float t = __expf(-2.0f * fabsf(uu));
    float th = (1.0f - t) / (1.0f + t);
    th = copysignf(th, uu);
    return 0.5f * v * (1.0f + th);
}

// ---------------------------------------------------------------------------
// 0) x fp32 -> bf16 cast
// ---------------------------------------------------------------------------
__global__ __launch_bounds__(256) void cast_kernel(
    const float4* __restrict__ s, ushort4* __restrict__ d)
{
    int i = blockIdx.x * 256 + threadIdx.x;
    float4 v = s[i];
    ushort4 o;
    o.x = f2bf(v.x); o.y = f2bf(v.y); o.z = f2bf(v.z); o.w = f2bf(v.w);
    d[i] = o;
}

// ---------------------------------------------------------------------------
// 1) Gating: fp64 accumulation so the top-K boundary ranking matches numpy
// ---------------------------------------------------------------------------
__global__ __launch_bounds__(256) void gating_kernel(
    const float* __restrict__ x, const float* __restrict__ wg,
    float* __restrict__ Sm)
{
    int wave = threadIdx.x >> 6;
    int lane = threadIdx.x & 63;
    int token = blockIdx.x * 4 + wave;
    int b = token >> 11, s = token & (Ss - 1);
    const float* xr = x + (size_t)token * Hh;

    double acc[Ee];
#pragma unroll
    for (int e = 0; e < Ee; ++e) acc[e] = 0.0;

    for (int i = 0; i < Hh / 64; ++i) {
        int h = lane + i * 64;
        double xv = (double)xr[h];
#pragma unroll
        for (int e = 0; e < Ee; ++e)
            acc[e] += xv * (double)wg[e * Hh + h];
    }
#pragma unroll
    for (int off = 32; off; off >>= 1) {
#pragma unroll
        for (int e = 0; e < Ee; ++e)
            acc[e] += __shfl_xor(acc[e], off, 64);
    }
    if (lane < Ee) {
        double m = acc[0];
#pragma unroll
        for (int e = 1; e < Ee; ++e) m = acc[e] > m ? acc[e] : m;
        double sum = 0.0;
#pragma unroll
        for (int e = 0; e < Ee; ++e) sum += exp(acc[e] - m);
        double v = exp(acc[lane] - m) / sum;
        Sm[((size_t)(b * Ee + lane)) * Ss + s] = (float)v;
    }
}

// ---------------------------------------------------------------------------
// 2) Top-K per (b,e): bitonic sort of 2048 keys; ties -> lower index first
// ---------------------------------------------------------------------------
__global__ __launch_bounds__(1024) void topk_kernel(
    const float* __restrict__ Sm, int* __restrict__ I, float* __restrict__ G)
{
    __shared__ unsigned long long keys[Ss];
    int be = blockIdx.x;
    const float* row = Sm + (size_t)be * Ss;
    for (int i = threadIdx.x; i < Ss; i += 1024) {
        unsigned int vb = __float_as_uint(row[i]);
        keys[i] = ((unsigned long long)vb << 32) | (unsigned int)(0xFFFFFFFFu - i);
    }
    __syncthreads();
    for (int k = 2; k <= Ss; k <<= 1) {
        for (int j = k >> 1; j > 0; j >>= 1) {
            for (int i = threadIdx.x; i < Ss; i += 1024) {
                int ixj = i ^ j;
                if (ixj > i) {
                    unsigned long long a = keys[i], c = keys[ixj];
                    bool desc = ((i & k) == 0);
                    if (desc ? (a < c) : (a > c)) { keys[i] = c; keys[ixj] = a; }
                }
            }
            __syncthreads();
        }
    }
    if (threadIdx.x < Kk) {
        unsigned long long kk = keys[threadIdx.x];
        I[(size_t)be * Kk + threadIdx.x] = (int)(0xFFFFFFFFu - (unsigned int)(kk & 0xFFFFFFFFu));
        G[(size_t)be * Kk + threadIdx.x] = __uint_as_float((unsigned int)(kk >> 32));
    }
}

// ---------------------------------------------------------------------------
// 3) Transpose + cast fp32 -> bf16, 64x64 tiles, coalesced 16B writes.
//    dst[z][c][r] = src[z][r][c]
// ---------------------------------------------------------------------------
__global__ __launch_bounds__(256) void transpose_cast_kernel(
    const float* __restrict__ src, unsigned short* __restrict__ dst, int R, int C)
{
    __shared__ float tile[64][68];   // stride 68: 16B-aligned rows, conflict-light
    int z = blockIdx.z;
    const float* s = src + (size_t)z * R * C;
    unsigned short* d = dst + (size_t)z * R * C;
    int c0 = blockIdx.x * 64, r0 = blockIdx.y * 64;
    int t = threadIdx.x;
#pragma unroll
    for (int p = 0; p < 4; ++p) {
        int g = p * 256 + t;
        int rr = g >> 4, cc = (g & 15) * 4;
        float4 v = *(const float4*)(s + (size_t)(r0 + rr) * C + c0 + cc);
        *(float4*)(&tile[rr][cc]) = v;
    }
    __syncthreads();
#pragma unroll
    for (int p = 0; p < 2; ++p) {
        int g = p * 256 + t;
        int cc = g >> 3, rr = (g & 7) * 8;
        u16x8 o;
#pragma unroll
        for (int k = 0; k < 8; ++k) o[k] = f2bf(tile[rr + k][cc]);
        *(u16x8*)(d + (size_t)(c0 + cc) * R + r0 + rr) = o;
    }
}

// ---------------------------------------------------------------------------
// GEMM: 256x256 tile, BK=64, 512 threads = 8 waves (2M x 4N), 8-phase
// software-pipelined K-loop (HipKittens-style schedule, m201 template):
//   - LDS 128 KiB: [buf(2)][mat A/B][half(2) of 128 rows x 64 k] bf16.
//   - per phase: ds_read ONE register subtile (A:8 or B:4 x ds_read_b128),
//     stage ONE half-tile (2 x global_load_lds_dwordx4 per wave),
//     barrier, setprio(1), 16 MFMA (one 64x32 C-quadrant x K=64), setprio(0),
//     barrier.  Counted s_waitcnt vmcnt(6) ONLY at phases 3 and 7 -> 3
//     half-tiles always in flight across barriers (never drained to 0).
//   - invariants: each phase stages the half-tile that was last ds_read in
//     the immediately preceding phase (dest-free by the inter-phase
//     barrier); every half is staged >= 4 phases before its first read and
//     covered by a vmcnt(6)+barrier in between.
//   - LDS XOR swizzle: 16B granule g of row r stored at g^(r&7); staging
//     pre-swizzles the per-lane GLOBAL source column (linear LDS dest),
//     reads XOR the granule index -> 2-way max bank aliasing (free).
// Per-wave output 128x64 = quadrants (q,c) in {0,1}^2 of 64x32.
// Fragments: A/B row = 16*frag + (lane&15), k = (lane>>4)*8 + j;
// C/D col = lane&15, row = (lane>>4)*4 + reg.
// ---------------------------------------------------------------------------

#define BAR { asm volatile("" ::: "memory"); __builtin_amdgcn_s_barrier(); asm volatile("" ::: "memory"); }
#define VMW6 asm volatile("s_waitcnt vmcnt(6)" ::: "memory");
#define VMW8 asm volatile("s_waitcnt vmcnt(8)" ::: "memory");
#define PRIO1 __builtin_amdgcn_s_setprio(1);
#define PRIO0 __builtin_amdgcn_s_setprio(0);

#define RD_A(bufi, h) { \
    _Pragma("unroll") for (int i = 0; i < 4; ++i) \
    _Pragma("unroll") for (int ks = 0; ks < 2; ++ks) \
        a[i][ks] = *(const bf16x8*)(ldsc + (bufi)*65536 + (h)*16384 \
            + ((wm64 + i*16 + fr) << 7) + (((ks*4 + quad) ^ fr7) << 4)); }

#define RD_B(bufi, h, B) { \
    _Pragma("unroll") for (int j = 0; j < 2; ++j) \
    _Pragma("unroll") for (int ks = 0; ks < 2; ++ks) \
        B[j][ks] = *(const bf16x8*)(ldsc + (bufi)*65536 + 32768 + (h)*16384 \
            + ((wn32 + j*16 + fr) << 7) + (((ks*4 + quad) ^ fr7) << 4)); }

#define STG_A(bufi, h, kt) { \
    char* _d = ldsm + (bufi)*65536 + (h)*16384 + stoff; \
    async_copy16(srcA[(h)*2+0] + (size_t)(kt)*64, _d); \
    async_copy16(srcA[(h)*2+1] + (size_t)(kt)*64, _d + 1024); }

#define STG_B(bufi, h, kt) { \
    char* _d = ldsm + (bufi)*65536 + 32768 + (h)*16384 + stoff; \
    async_copy16(srcB[(h)*2+0] + (size_t)(kt)*64, _d); \
    async_copy16(srcB[(h)*2+1] + (size_t)(kt)*64, _d + 1024); }

#define MFMA_Q(q, c, B) { \
    _Pragma("unroll") for (int i = 0; i < 4; ++i) \
    _Pragma("unroll") for (int j = 0; j < 2; ++j) \
    _Pragma("unroll") for (int ks = 0; ks < 2; ++ks) \
        acc[q][c][i][j] = __builtin_amdgcn_mfma_f32_16x16x32_bf16( \
            a[i][ks], B[j][ks], acc[q][c][i][j], 0, 0, 0); }

// prologue: buf0 <- tile 0, buf1 <- tile 1 (16 loads/wave); wait so buf0 is
// landed (8 left = buf1); read B0 regs; then 8-phase steady state.
#define GEMM_MAIN(NTILES) \
    f32x4 acc[2][2][4][2] = {}; \
    bf16x8 a[4][2], br0[2][2], br1[2][2]; \
    STG_B(0,0,0) STG_A(0,0,0) STG_B(0,1,0) STG_A(0,1,0) \
    STG_B(1,0,1) STG_A(1,0,1) STG_B(1,1,1) STG_A(1,1,1) \
    VMW8 BAR \
    RD_B(0,0,br0) \
    for (int t2 = 0; t2 < (NTILES); t2 += 2) { \
        const int ka = (t2 + 2 < (NTILES)) ? t2 + 2 : 0; \
        const int kb = (t2 + 3 < (NTILES)) ? t2 + 3 : 0; \
        RD_A(0,0)      STG_B(0,0,ka)      BAR PRIO1 MFMA_Q(0,0,br0) PRIO0 BAR \
        RD_B(0,1,br1)  STG_A(0,0,ka)      BAR PRIO1 MFMA_Q(0,1,br1) PRIO0 BAR \
        RD_A(0,1)      STG_B(0,1,ka) VMW6 BAR PRIO1 MFMA_Q(1,0,br0) PRIO0 BAR \
        RD_B(1,0,br0)  STG_A(0,1,ka)      BAR PRIO1 MFMA_Q(1,1,br1) PRIO0 BAR \
        RD_A(1,0)      STG_B(1,0,kb)      BAR PRIO1 MFMA_Q(0,0,br0) PRIO0 BAR \
        RD_B(1,1,br1)  STG_A(1,0,kb)      BAR PRIO1 MFMA_Q(0,1,br1) PRIO0 BAR \
        RD_A(1,1)      STG_B(1,1,kb) VMW6 BAR PRIO1 MFMA_Q(1,0,br0) PRIO0 BAR \
        RD_B(0,0,br0)  STG_A(1,1,kb)      BAR PRIO1 MFMA_Q(1,1,br1) PRIO0 BAR \
    }

// common per-thread geometry + bijective XCD-chunk swizzle (grid % 8 == 0)
#define GEMM_PREAMBLE \
    const int t = threadIdx.x; \
    const int lane = t & 63, w = t >> 6; \
    const int wm64 = (w >> 2) * 64, wn32 = (w & 3) * 32; \
    const int fr = lane & 15, quad = lane >> 4, fr7 = lane & 7; \
    const int l3 = lane >> 3; \
    const int sc = ((lane & 7) ^ l3) * 8; \
    const int stoff = w * 2048; \
    const int nx = gridDim.x, ny = gridDim.y; \
    const int nwg = nx * ny * gridDim.z; \
    const int flat = blockIdx.x + nx * (blockIdx.y + ny * blockIdx.z); \
    const int lid = (flat & 7) * (nwg >> 3) + (flat >> 3); \
    const int tn = lid % nx; \
    const int _rest = lid / nx; \
    const int by = _rest % ny; \
    const int e = _rest / ny; \
    const int bl = by >> 1, tm = by & 1; \
    const int b = b0 + bl; \
    __shared__ __align__(128) char lds[131072]; \
    const char* ldsc = lds; char* ldsm = lds;

__global__ __launch_bounds__(512, 2) void gemm1_kernel(
    const unsigned short* __restrict__ xb,   // [B,S,H] bf16
    const unsigned short* __restrict__ w1t,  // [E,F,H] bf16
    const float* __restrict__ b1, const int* __restrict__ I,
    unsigned short* __restrict__ h1,         // [gb,E,K,F] bf16
    int b0)
{
    GEMM_PREAMBLE
    const int ib = (b * Ee + e) * Kk + tm * 256;
    const unsigned short* srcA[4];
    const unsigned short* srcB[4];
#pragma unroll
    for (int h = 0; h < 2; ++h)
#pragma unroll
        for (int inst = 0; inst < 2; ++inst) {
            int r = h * 128 + w * 16 + inst * 8 + l3;
            srcA[h * 2 + inst] = xb + ((size_t)(b * Ss + I[ib + r])) * Hh + sc;
            srcB[h * 2 + inst] = w1t + ((size_t)e * Ff + tn * 256 + r) * Hh + sc;
        }

    GEMM_MAIN(Hh / 64)

    float bias[2][2];
#pragma unroll
    for (int c = 0; c < 2; ++c)
#pragma unroll
        for (int j = 0; j < 2; ++j)
            bias[c][j] = b1[(size_t)e * Ff + tn * 256 + c * 128 + wn32 + j * 16 + fr];
#pragma unroll
    for (int q = 0; q < 2; ++q)
#pragma unroll
        for (int i = 0; i < 4; ++i)
#pragma unroll
            for (int r = 0; r < 4; ++r) {
                int m = tm * 256 + q * 128 + wm64 + i * 16 + quad * 4 + r;
                unsigned short* orow = h1 + (((size_t)bl * Ee + e) * Kk + m) * Ff + tn * 256;
#pragma unroll
                for (int c = 0; c < 2; ++c)
#pragma unroll
                    for (int j = 0; j < 2; ++j)
                        orow[c * 128 + wn32 + j * 16 + fr] =
                            f2bf(gelu(acc[q][c][i][j][r] + bias[c][j]));
            }
}

__global__ __launch_bounds__(512, 2) void gemm2_kernel(
    const unsigned short* __restrict__ h1,   // [gb,E,K,F] bf16
    const unsigned short* __restrict__ w2t,  // [E,H,F] bf16
    const float* __restrict__ b2, const int* __restrict__ I, const float* __restrict__ G,
    float* __restrict__ out, int b0)
{
    GEMM_PREAMBLE
    const unsigned short* srcA[4];
    const unsigned short* srcB[4];
#pragma unroll
    for (int h = 0; h < 2; ++h)
#pragma unroll
        for (int inst = 0; inst < 2; ++inst) {
            int r = h * 128 + w * 16 + inst * 8 + l3;
            srcA[h * 2 + inst] = h1 + (((size_t)bl * Ee + e) * Kk + tm * 256 + r) * Ff + sc;
            srcB[h * 2 + inst] = w2t + ((size_t)e * Hh + tn * 256 + r) * Ff + sc;
        }

    GEMM_MAIN(Ff / 64)

    float bias[2][2];
#pragma unroll
    for (int c = 0; c < 2; ++c)
#pragma unroll
        for (int j = 0; j < 2; ++j)
            bias[c][j] = b2[(size_t)e * Hh + tn * 256 + c * 128 + wn32 + j * 16 + fr];
#pragma unroll
    for (int q = 0; q < 2; ++q)
#pragma unroll
        for (int i = 0; i < 4; ++i)
#pragma unroll
            for (int r = 0; r < 4; ++r) {
                int m = tm * 256 + q * 128 + wm64 + i * 16 + quad * 4 + r;
                int slot = (b * Ee + e) * Kk + m;
                float gate = G[slot];
                int tok = I[slot];
                float* orow = out + ((size_t)(b * Ss + tok)) * Hh + tn * 256;
#pragma unroll
                for (int c = 0; c < 2; ++c)
#pragma unroll
                    for (int j = 0; j < 2; ++j)
                        atomicAdd(&orow[c * 128 + wn32 + j * 16 + fr],
                                  (acc[q][c][i][j][r] + bias[c][j]) * gate);
            }
}

// ---------------------------------------------------------------------------
extern "C" void kernel_launch(void* const* d_in, const int* in_sizes, int n_in,
                              void* d_out, int out_size, void* d_ws, size_t ws_size,
                              hipStream_t stream) {
    const float* x  = (const float*)d_in[0];   // [B,S,H]
    const float* Wg = (const float*)d_in[1];   // [E,H]
    const float* W1 = (const float*)d_in[2];   // [E,H,F]
    const float* b1 = (const float*)d_in[3];   // [E,F]
    const float* W2 = (const float*)d_in[4];   // [E,F,H]
    const float* b2 = (const float*)d_in[5];   // [E,H]
    float* out = (float*)d_out;                // [B,S,H]

    size_t off = 0;
    char* base = (char*)d_ws;
    auto alloc = [&](size_t bytes) -> void* {
        void* p = base + off;
        off += (bytes + 255) & ~(size_t)255;
        return p;
    };
    float* Sm  = (float*)alloc((size_t)Bb * Ee * Ss * 4);
    int*   I   = (int*)alloc((size_t)Bb * Ee * Kk * 4);
    float* G   = (float*)alloc((size_t)Bb * Ee * Kk * 4);
    unsigned short* W1T = (unsigned short*)alloc((size_t)Ee * Ff * Hh * 2); // [E,F,H]
    unsigned short* W2T = (unsigned short*)alloc((size_t)Ee * Hh * Ff * 2); // [E,H,F]
    unsigned short* xb  = (unsigned short*)alloc((size_t)Bb * Ss * Hh * 2); // [B,S,H]
    size_t fixed = off;
    // adaptive batch-group size for h1 (deterministic: ws_size is constant)
    size_t h1_per_b = (size_t)Ee * Kk * Ff * 2;   // 32 MiB
    int gb = 4;
    while (gb > 1 && fixed + (size_t)gb * h1_per_b > ws_size) gb >>= 1;
    unsigned short* h1 = (unsigned short*)alloc((size_t)gb * h1_per_b);
    if (off > ws_size) return;

    hipMemsetAsync(d_out, 0, (size_t)out_size * sizeof(float), stream);

    cast_kernel<<<(Bb * Ss * Hh) / 1024, 256, 0, stream>>>((const float4*)x, (ushort4*)xb);
    gating_kernel<<<(Bb * Ss) / 4, 256, 0, stream>>>(x, Wg, Sm);
    topk_kernel<<<Bb * Ee, 1024, 0, stream>>>(Sm, I, G);
    transpose_cast_kernel<<<dim3(Ff / 64, Hh / 64, Ee), 256, 0, stream>>>(W1, W1T, Hh, Ff);
    transpose_cast_kernel<<<dim3(Hh / 64, Ff / 64, Ee), 256, 0, stream>>>(W2, W2T, Ff, Hh);

    for (int g = 0; g < Bb / gb; ++g) {
        gemm1_kernel<<<dim3(Ff / 256, 2 * gb, Ee), 512, 0, stream>>>(xb, W1T, b1, I, h1, g * gb);
        gemm2_kernel<<<dim3(Hh / 256, 2 * gb, Ee), 512, 0, stream>>>(h1, W2T, b2, I, G, out, g * gb);
    }
}

// Round 2
// 663.505 us; speedup vs baseline: 1.2567x; 1.0453x over previous
//
#include <hip/hip_runtime.h>
#include <math.h>
#include <cstdint>

// Problem constants (from reference)
#define Bb 4
#define Ss 2048
#define Hh 1024
#define Ee 8
#define Kk 512
#define Ff 4096

typedef short bf16x8 __attribute__((ext_vector_type(8)));       // 8 bf16 in 4 VGPRs
typedef unsigned short u16x8 __attribute__((ext_vector_type(8)));
typedef float f32x4 __attribute__((ext_vector_type(4)));

// fp32 -> bf16 round-to-nearest-even (bit form)
__device__ __forceinline__ unsigned short f2bf(float f) {
    unsigned int u = __float_as_uint(f);
    u = (u + 0x7FFFu + ((u >> 16) & 1u)) >> 16;
    return (unsigned short)u;
}

// async 16B global->LDS copy (global_load_lds_dwordx4). LDS dest is
// wave-uniform base + lane*16 (m104/m108). Source address is per-lane.
__device__ __forceinline__ void async_copy16(const void* gsrc, void* ldst) {
    auto* g = reinterpret_cast<__attribute__((address_space(1))) void*>(
        reinterpret_cast<uintptr_t>(gsrc));
    auto* l = reinterpret_cast<__attribute__((address_space(3))) void*>(
        (unsigned int)reinterpret_cast<uintptr_t>(ldst));
    __builtin_amdgcn_global_load_lds(g, l, 16, 0, 0);
}

// exact tanh-gelu via the sigmoid identity: 0.5*(1+tanh(u)) == sigma(2u)
//   gelu(v) = v * sigma(2u) = v * rcp(1 + e^{-2u}),
//   -2u = v * (c1 + c2*v^2),  c1 = -2*0.7978845608, c2 = c1*0.044715
// 7 VALU insts (2 transcendental), sign-safe for all v (inf -> 0 or v).
__device__ __forceinline__ float gelu(float v) {
    float v2 = v * v;
    float w = v * fmaf(v2, -0.0713548310f, -1.5957691216f);
    float t = __expf(w);
    return v * __builtin_amdgcn_rcpf(1.0f + t);
}

// ---------------------------------------------------------------------------
// 0) x fp32 -> bf16 cast
// ---------------------------------------------------------------------------
__global__ __launch_bounds__(256) void cast_kernel(
    const float4* __restrict__ s, ushort4* __restrict__ d)
{
    int i = blockIdx.x * 256 + threadIdx.x;
    float4 v = s[i];
    ushort4 o;
    o.x = f2bf(v.x); o.y = f2bf(v.y); o.z = f2bf(v.z); o.w = f2bf(v.w);
    d[i] = o;
}

// ---------------------------------------------------------------------------
// 1) Gating: fp64 accumulation so the top-K boundary ranking matches numpy
// ---------------------------------------------------------------------------
__global__ __launch_bounds__(256) void gating_kernel(
    const float* __restrict__ x, const float* __restrict__ wg,
    float* __restrict__ Sm)
{
    int wave = threadIdx.x >> 6;
    int lane = threadIdx.x & 63;
    int token = blockIdx.x * 4 + wave;
    int b = token >> 11, s = token & (Ss - 1);
    const float* xr = x + (size_t)token * Hh;

    double acc[Ee];
#pragma unroll
    for (int e = 0; e < Ee; ++e) acc[e] = 0.0;

    for (int i = 0; i < Hh / 64; ++i) {
        int h = lane + i * 64;
        double xv = (double)xr[h];
#pragma unroll
        for (int e = 0; e < Ee; ++e)
            acc[e] += xv * (double)wg[e * Hh + h];
    }
#pragma unroll
    for (int off = 32; off; off >>= 1) {
#pragma unroll
        for (int e = 0; e < Ee; ++e)
            acc[e] += __shfl_xor(acc[e], off, 64);
    }
    if (lane < Ee) {
        double m = acc[0];
#pragma unroll
        for (int e = 1; e < Ee; ++e) m = acc[e] > m ? acc[e] : m;
        double sum = 0.0;
#pragma unroll
        for (int e = 0; e < Ee; ++e) sum += exp(acc[e] - m);
        double v = exp(acc[lane] - m) / sum;
        Sm[((size_t)(b * Ee + lane)) * Ss + s] = (float)v;
    }
}

// ---------------------------------------------------------------------------
// 2) Top-K per (b,e): bitonic sort of 2048 keys; ties -> lower index first
// ---------------------------------------------------------------------------
__global__ __launch_bounds__(1024) void topk_kernel(
    const float* __restrict__ Sm, int* __restrict__ I, float* __restrict__ G)
{
    __shared__ unsigned long long keys[Ss];
    int be = blockIdx.x;
    const float* row = Sm + (size_t)be * Ss;
    for (int i = threadIdx.x; i < Ss; i += 1024) {
        unsigned int vb = __float_as_uint(row[i]);
        keys[i] = ((unsigned long long)vb << 32) | (unsigned int)(0xFFFFFFFFu - i);
    }
    __syncthreads();
    for (int k = 2; k <= Ss; k <<= 1) {
        for (int j = k >> 1; j > 0; j >>= 1) {
            for (int i = threadIdx.x; i < Ss; i += 1024) {
                int ixj = i ^ j;
                if (ixj > i) {
                    unsigned long long a = keys[i], c = keys[ixj];
                    bool desc = ((i & k) == 0);
                    if (desc ? (a < c) : (a > c)) { keys[i] = c; keys[ixj] = a; }
                }
            }
            __syncthreads();
        }
    }
    if (threadIdx.x < Kk) {
        unsigned long long kk = keys[threadIdx.x];
        I[(size_t)be * Kk + threadIdx.x] = (int)(0xFFFFFFFFu - (unsigned int)(kk & 0xFFFFFFFFu));
        G[(size_t)be * Kk + threadIdx.x] = __uint_as_float((unsigned int)(kk >> 32));
    }
}

// ---------------------------------------------------------------------------
// 3) Transpose + cast fp32 -> bf16, 128x128 tiles.
//    dst[z][c][r] = bf16(src[z][r][c])
//    LDS holds the tile ALREADY transposed as packed bf16 row-pairs:
//      tileT[c*65 + rp] = bf16(src[2rp][c]) | bf16(src[2rp+1][c]) << 16
//    Load : 512B-contiguous float4 reads (2 rows/thread-pass), cast+pack,
//           4x ds_write_b32 (4-way bank alias worst case on stores).
//    Write: 4x conflict-free ds_read_b32 -> u16x8 -> 256B-contiguous stores.
// ---------------------------------------------------------------------------
__global__ __launch_bounds__(256) void transpose_cast_kernel(
    const float* __restrict__ src, unsigned short* __restrict__ dst, int R, int C)
{
    __shared__ unsigned int tileT[128 * 65];   // 33 KB, 4 blocks/CU
    int z = blockIdx.z;
    const float* s = src + (size_t)z * R * C;
    unsigned short* d = dst + (size_t)z * R * C;
    int c0 = blockIdx.x * 128, r0 = blockIdx.y * 128;
    int t = threadIdx.x;

    int cq = t & 31;            // 16B column chunk within a row
    int rp0 = t >> 5;           // row-pair base (0..7)
#pragma unroll
    for (int p = 0; p < 8; ++p) {
        int rp = rp0 + p * 8;   // 0..63
        const float* s0 = s + (size_t)(r0 + 2 * rp) * C + c0 + cq * 4;
        float4 a = *(const float4*)s0;
        float4 b = *(const float4*)(s0 + C);
        const float* af = (const float*)&a;
        const float* bf = (const float*)&b;
#pragma unroll
        for (int i = 0; i < 4; ++i) {
            unsigned int lo = f2bf(af[i]);
            unsigned int hi = f2bf(bf[i]);
            tileT[(cq * 4 + i) * 65 + rp] = lo | (hi << 16);
        }
    }
    __syncthreads();

    int cw0 = t >> 4;           // column base (0..15), +16 per pass
    int rseg = t & 15;          // 16B r-chunk (8 elems)
#pragma unroll
    for (int p = 0; p < 8; ++p) {
        int c = cw0 + p * 16;
        u16x8 o;
#pragma unroll
        for (int k = 0; k < 4; ++k) {
            unsigned int dd = tileT[c * 65 + rseg * 4 + k];
            o[2 * k]     = (unsigned short)(dd & 0xFFFFu);
            o[2 * k + 1] = (unsigned short)(dd >> 16);
        }
        *(u16x8*)(d + (size_t)(c0 + c) * R + r0 + rseg * 8) = o;
    }
}

// ---------------------------------------------------------------------------
// GEMM: 256x256 tile, BK=64, 512 threads = 8 waves (2M x 4N), 8-phase
// software-pipelined K-loop (HipKittens-style schedule, m201 template):
//   - LDS 128 KiB: [buf(2)][mat A/B][half(2) of 128 rows x 64 k] bf16.
//   - per phase: ds_read ONE register subtile (A:8 or B:4 x ds_read_b128),
//     stage ONE half-tile (2 x global_load_lds_dwordx4 per wave),
//     barrier, setprio(1), 16 MFMA (one 64x32 C-quadrant x K=64), setprio(0),
//     barrier.  Counted s_waitcnt vmcnt(6) ONLY at phases 3 and 7 -> 3
//     half-tiles always in flight across barriers (never drained to 0).
//   - invariants: each phase stages the half-tile that was last ds_read in
//     the immediately preceding phase (dest-free by the inter-phase
//     barrier); every half is staged >= 4 phases before its first read and
//     covered by a vmcnt(6)+barrier in between.
//   - LDS XOR swizzle: 16B granule g of row r stored at g^(r&7); staging
//     pre-swizzles the per-lane GLOBAL source column (linear LDS dest),
//     reads XOR the granule index -> 2-way max bank aliasing (free).
// Per-wave output 128x64 = quadrants (q,c) in {0,1}^2 of 64x32.
// Fragments: A/B row = 16*frag + (lane&15), k = (lane>>4)*8 + j;
// C/D col = lane&15, row = (lane>>4)*4 + reg.
// ---------------------------------------------------------------------------

#define BAR { asm volatile("" ::: "memory"); __builtin_amdgcn_s_barrier(); asm volatile("" ::: "memory"); }
#define VMW6 asm volatile("s_waitcnt vmcnt(6)" ::: "memory");
#define VMW8 asm volatile("s_waitcnt vmcnt(8)" ::: "memory");
#define PRIO1 __builtin_amdgcn_s_setprio(1);
#define PRIO0 __builtin_amdgcn_s_setprio(0);

#define RD_A(bufi, h) { \
    _Pragma("unroll") for (int i = 0; i < 4; ++i) \
    _Pragma("unroll") for (int ks = 0; ks < 2; ++ks) \
        a[i][ks] = *(const bf16x8*)(ldsc + (bufi)*65536 + (h)*16384 \
            + ((wm64 + i*16 + fr) << 7) + (((ks*4 + quad) ^ fr7) << 4)); }

#define RD_B(bufi, h, B) { \
    _Pragma("unroll") for (int j = 0; j < 2; ++j) \
    _Pragma("unroll") for (int ks = 0; ks < 2; ++ks) \
        B[j][ks] = *(const bf16x8*)(ldsc + (bufi)*65536 + 32768 + (h)*16384 \
            + ((wn32 + j*16 + fr) << 7) + (((ks*4 + quad) ^ fr7) << 4)); }

#define STG_A(bufi, h, kt) { \
    char* _d = ldsm + (bufi)*65536 + (h)*16384 + stoff; \
    async_copy16(srcA[(h)*2+0] + (size_t)(kt)*64, _d); \
    async_copy16(srcA[(h)*2+1] + (size_t)(kt)*64, _d + 1024); }

#define STG_B(bufi, h, kt) { \
    char* _d = ldsm + (bufi)*65536 + 32768 + (h)*16384 + stoff; \
    async_copy16(srcB[(h)*2+0] + (size_t)(kt)*64, _d); \
    async_copy16(srcB[(h)*2+1] + (size_t)(kt)*64, _d + 1024); }

#define MFMA_Q(q, c, B) { \
    _Pragma("unroll") for (int i = 0; i < 4; ++i) \
    _Pragma("unroll") for (int j = 0; j < 2; ++j) \
    _Pragma("unroll") for (int ks = 0; ks < 2; ++ks) \
        acc[q][c][i][j] = __builtin_amdgcn_mfma_f32_16x16x32_bf16( \
            a[i][ks], B[j][ks], acc[q][c][i][j], 0, 0, 0); }

// prologue: buf0 <- tile 0, buf1 <- tile 1 (16 loads/wave); wait so buf0 is
// landed (8 left = buf1); read B0 regs; then 8-phase steady state.
#define GEMM_MAIN(NTILES) \
    f32x4 acc[2][2][4][2] = {}; \
    bf16x8 a[4][2], br0[2][2], br1[2][2]; \
    STG_B(0,0,0) STG_A(0,0,0) STG_B(0,1,0) STG_A(0,1,0) \
    STG_B(1,0,1) STG_A(1,0,1) STG_B(1,1,1) STG_A(1,1,1) \
    VMW8 BAR \
    RD_B(0,0,br0) \
    for (int t2 = 0; t2 < (NTILES); t2 += 2) { \
        const int ka = (t2 + 2 < (NTILES)) ? t2 + 2 : 0; \
        const int kb = (t2 + 3 < (NTILES)) ? t2 + 3 : 0; \
        RD_A(0,0)      STG_B(0,0,ka)      BAR PRIO1 MFMA_Q(0,0,br0) PRIO0 BAR \
        RD_B(0,1,br1)  STG_A(0,0,ka)      BAR PRIO1 MFMA_Q(0,1,br1) PRIO0 BAR \
        RD_A(0,1)      STG_B(0,1,ka) VMW6 BAR PRIO1 MFMA_Q(1,0,br0) PRIO0 BAR \
        RD_B(1,0,br0)  STG_A(0,1,ka)      BAR PRIO1 MFMA_Q(1,1,br1) PRIO0 BAR \
        RD_A(1,0)      STG_B(1,0,kb)      BAR PRIO1 MFMA_Q(0,0,br0) PRIO0 BAR \
        RD_B(1,1,br1)  STG_A(1,0,kb)      BAR PRIO1 MFMA_Q(0,1,br1) PRIO0 BAR \
        RD_A(1,1)      STG_B(1,1,kb) VMW6 BAR PRIO1 MFMA_Q(1,0,br0) PRIO0 BAR \
        RD_B(0,0,br0)  STG_A(1,1,kb)      BAR PRIO1 MFMA_Q(1,1,br1) PRIO0 BAR \
    }

// common per-thread geometry + bijective XCD-chunk swizzle (grid % 8 == 0)
#define GEMM_PREAMBLE \
    const int t = threadIdx.x; \
    const int lane = t & 63, w = t >> 6; \
    const int wm64 = (w >> 2) * 64, wn32 = (w & 3) * 32; \
    const int fr = lane & 15, quad = lane >> 4, fr7 = lane & 7; \
    const int l3 = lane >> 3; \
    const int sc = ((lane & 7) ^ l3) * 8; \
    const int stoff = w * 2048; \
    const int nx = gridDim.x, ny = gridDim.y; \
    const int nwg = nx * ny * gridDim.z; \
    const int flat = blockIdx.x + nx * (blockIdx.y + ny * blockIdx.z); \
    const int lid = (flat & 7) * (nwg >> 3) + (flat >> 3); \
    const int tn = lid % nx; \
    const int _rest = lid / nx; \
    const int by = _rest % ny; \
    const int e = _rest / ny; \
    const int bl = by >> 1, tm = by & 1; \
    const int b = b0 + bl; \
    __shared__ __align__(128) char lds[131072]; \
    const char* ldsc = lds; char* ldsm = lds;

__global__ __launch_bounds__(512, 2) void gemm1_kernel(
    const unsigned short* __restrict__ xb,   // [B,S,H] bf16
    const unsigned short* __restrict__ w1t,  // [E,F,H] bf16
    const float* __restrict__ b1, const int* __restrict__ I,
    unsigned short* __restrict__ h1,         // [gb,E,K,F] bf16
    int b0)
{
    GEMM_PREAMBLE
    const int ib = (b * Ee + e) * Kk + tm * 256;
    const unsigned short* srcA[4];
    const unsigned short* srcB[4];
#pragma unroll
    for (int h = 0; h < 2; ++h)
#pragma unroll
        for (int inst = 0; inst < 2; ++inst) {
            int r = h * 128 + w * 16 + inst * 8 + l3;
            srcA[h * 2 + inst] = xb + ((size_t)(b * Ss + I[ib + r])) * Hh + sc;
            srcB[h * 2 + inst] = w1t + ((size_t)e * Ff + tn * 256 + r) * Hh + sc;
        }

    GEMM_MAIN(Hh / 64)

    float bias[2][2];
#pragma unroll
    for (int c = 0; c < 2; ++c)
#pragma unroll
        for (int j = 0; j < 2; ++j)
            bias[c][j] = b1[(size_t)e * Ff + tn * 256 + c * 128 + wn32 + j * 16 + fr];
#pragma unroll
    for (int q = 0; q < 2; ++q)
#pragma unroll
        for (int i = 0; i < 4; ++i)
#pragma unroll
            for (int r = 0; r < 4; ++r) {
                int m = tm * 256 + q * 128 + wm64 + i * 16 + quad * 4 + r;
                unsigned short* orow = h1 + (((size_t)bl * Ee + e) * Kk + m) * Ff + tn * 256;
#pragma unroll
                for (int c = 0; c < 2; ++c)
#pragma unroll
                    for (int j = 0; j < 2; ++j)
                        orow[c * 128 + wn32 + j * 16 + fr] =
                            f2bf(gelu(acc[q][c][i][j][r] + bias[c][j]));
            }
}

__global__ __launch_bounds__(512, 2) void gemm2_kernel(
    const unsigned short* __restrict__ h1,   // [gb,E,K,F] bf16
    const unsigned short* __restrict__ w2t,  // [E,H,F] bf16
    const float* __restrict__ b2, const int* __restrict__ I, const float* __restrict__ G,
    float* __restrict__ out, int b0)
{
    GEMM_PREAMBLE
    const unsigned short* srcA[4];
    const unsigned short* srcB[4];
#pragma unroll
    for (int h = 0; h < 2; ++h)
#pragma unroll
        for (int inst = 0; inst < 2; ++inst) {
            int r = h * 128 + w * 16 + inst * 8 + l3;
            srcA[h * 2 + inst] = h1 + (((size_t)bl * Ee + e) * Kk + tm * 256 + r) * Ff + sc;
            srcB[h * 2 + inst] = w2t + ((size_t)e * Hh + tn * 256 + r) * Ff + sc;
        }

    GEMM_MAIN(Ff / 64)

    float bias[2][2];
#pragma unroll
    for (int c = 0; c < 2; ++c)
#pragma unroll
        for (int j = 0; j < 2; ++j)
            bias[c][j] = b2[(size_t)e * Hh + tn * 256 + c * 128 + wn32 + j * 16 + fr];
#pragma unroll
    for (int q = 0; q < 2; ++q)
#pragma unroll
        for (int i = 0; i < 4; ++i)
#pragma unroll
            for (int r = 0; r < 4; ++r) {
                int m = tm * 256 + q * 128 + wm64 + i * 16 + quad * 4 + r;
                int slot = (b * Ee + e) * Kk + m;
                float gate = G[slot];
                int tok = I[slot];
                float* orow = out + ((size_t)(b * Ss + tok)) * Hh + tn * 256;
#pragma unroll
                for (int c = 0; c < 2; ++c)
#pragma unroll
                    for (int j = 0; j < 2; ++j)
                        atomicAdd(&orow[c * 128 + wn32 + j * 16 + fr],
                                  (acc[q][c][i][j][r] + bias[c][j]) * gate);
            }
}

// ---------------------------------------------------------------------------
extern "C" void kernel_launch(void* const* d_in, const int* in_sizes, int n_in,
                              void* d_out, int out_size, void* d_ws, size_t ws_size,
                              hipStream_t stream) {
    const float* x  = (const float*)d_in[0];   // [B,S,H]
    const float* Wg = (const float*)d_in[1];   // [E,H]
    const float* W1 = (const float*)d_in[2];   // [E,H,F]
    const float* b1 = (const float*)d_in[3];   // [E,F]
    const float* W2 = (const float*)d_in[4];   // [E,F,H]
    const float* b2 = (const float*)d_in[5];   // [E,H]
    float* out = (float*)d_out;                // [B,S,H]

    size_t off = 0;
    char* base = (char*)d_ws;
    auto alloc = [&](size_t bytes) -> void* {
        void* p = base + off;
        off += (bytes + 255) & ~(size_t)255;
        return p;
    };
    float* Sm  = (float*)alloc((size_t)Bb * Ee * Ss * 4);
    int*   I   = (int*)alloc((size_t)Bb * Ee * Kk * 4);
    float* G   = (float*)alloc((size_t)Bb * Ee * Kk * 4);
    unsigned short* W1T = (unsigned short*)alloc((size_t)Ee * Ff * Hh * 2); // [E,F,H]
    unsigned short* W2T = (unsigned short*)alloc((size_t)Ee * Hh * Ff * 2); // [E,H,F]
    unsigned short* xb  = (unsigned short*)alloc((size_t)Bb * Ss * Hh * 2); // [B,S,H]
    size_t fixed = off;
    // adaptive batch-group size for h1 (deterministic: ws_size is constant)
    size_t h1_per_b = (size_t)Ee * Kk * Ff * 2;   // 32 MiB
    int gb = 4;
    while (gb > 1 && fixed + (size_t)gb * h1_per_b > ws_size) gb >>= 1;
    unsigned short* h1 = (unsigned short*)alloc((size_t)gb * h1_per_b);
    if (off > ws_size) return;

    hipMemsetAsync(d_out, 0, (size_t)out_size * sizeof(float), stream);

    cast_kernel<<<(Bb * Ss * Hh) / 1024, 256, 0, stream>>>((const float4*)x, (ushort4*)xb);
    gating_kernel<<<(Bb * Ss) / 4, 256, 0, stream>>>(x, Wg, Sm);
    topk_kernel<<<Bb * Ee, 1024, 0, stream>>>(Sm, I, G);
    transpose_cast_kernel<<<dim3(Ff / 128, Hh / 128, Ee), 256, 0, stream>>>(W1, W1T, Hh, Ff);
    transpose_cast_kernel<<<dim3(Hh / 128, Ff / 128, Ee), 256, 0, stream>>>(W2, W2T, Ff, Hh);

    for (int g = 0; g < Bb / gb; ++g) {
        gemm1_kernel<<<dim3(Ff / 256, 2 * gb, Ee), 512, 0, stream>>>(xb, W1T, b1, I, h1, g * gb);
        gemm2_kernel<<<dim3(Hh / 256, 2 * gb, Ee), 512, 0, stream>>>(h1, W2T, b2, I, G, out, g * gb);
    }
}

// Round 3
// 654.656 us; speedup vs baseline: 1.2737x; 1.0135x over previous
//
#include <hip/hip_runtime.h>
#include <math.h>
#include <cstdint>

// Problem constants (from reference)
#define Bb 4
#define Ss 2048
#define Hh 1024
#define Ee 8
#define Kk 512
#define Ff 4096

typedef short bf16x8 __attribute__((ext_vector_type(8)));       // 8 bf16 in 4 VGPRs
typedef unsigned short u16x8 __attribute__((ext_vector_type(8)));
typedef float f32x4 __attribute__((ext_vector_type(4)));

// fp32 -> bf16 round-to-nearest-even (bit form)
__device__ __forceinline__ unsigned short f2bf(float f) {
    unsigned int u = __float_as_uint(f);
    u = (u + 0x7FFFu + ((u >> 16) & 1u)) >> 16;
    return (unsigned short)u;
}

// async 16B global->LDS copy (global_load_lds_dwordx4). LDS dest is
// wave-uniform base + lane*16 (m104/m108). Source address is per-lane.
__device__ __forceinline__ void async_copy16(const void* gsrc, void* ldst) {
    auto* g = reinterpret_cast<__attribute__((address_space(1))) void*>(
        reinterpret_cast<uintptr_t>(gsrc));
    auto* l = reinterpret_cast<__attribute__((address_space(3))) void*>(
        (unsigned int)reinterpret_cast<uintptr_t>(ldst));
    __builtin_amdgcn_global_load_lds(g, l, 16, 0, 0);
}

// exact tanh-gelu via the sigmoid identity: 0.5*(1+tanh(u)) == sigma(2u)
//   gelu(v) = v * rcp(1 + e^{-2u}),  -2u = v*(c1 + c2*v^2)
__device__ __forceinline__ float gelu(float v) {
    float v2 = v * v;
    float w = v * fmaf(v2, -0.0713548310f, -1.5957691216f);
    float t = __expf(w);
    return v * __builtin_amdgcn_rcpf(1.0f + t);
}

// ---------------------------------------------------------------------------
// 0) x fp32 -> bf16 cast
// ---------------------------------------------------------------------------
__global__ __launch_bounds__(256) void cast_kernel(
    const float4* __restrict__ s, ushort4* __restrict__ d)
{
    int i = blockIdx.x * 256 + threadIdx.x;
    float4 v = s[i];
    ushort4 o;
    o.x = f2bf(v.x); o.y = f2bf(v.y); o.z = f2bf(v.z); o.w = f2bf(v.w);
    d[i] = o;
}

// ---------------------------------------------------------------------------
// 1) Gating: fp64 accumulation so the top-K boundary ranking matches numpy
// ---------------------------------------------------------------------------
__global__ __launch_bounds__(256) void gating_kernel(
    const float* __restrict__ x, const float* __restrict__ wg,
    float* __restrict__ Sm)
{
    int wave = threadIdx.x >> 6;
    int lane = threadIdx.x & 63;
    int token = blockIdx.x * 4 + wave;
    int b = token >> 11, s = token & (Ss - 1);
    const float* xr = x + (size_t)token * Hh;

    double acc[Ee];
#pragma unroll
    for (int e = 0; e < Ee; ++e) acc[e] = 0.0;

    for (int i = 0; i < Hh / 64; ++i) {
        int h = lane + i * 64;
        double xv = (double)xr[h];
#pragma unroll
        for (int e = 0; e < Ee; ++e)
            acc[e] += xv * (double)wg[e * Hh + h];
    }
#pragma unroll
    for (int off = 32; off; off >>= 1) {
#pragma unroll
        for (int e = 0; e < Ee; ++e)
            acc[e] += __shfl_xor(acc[e], off, 64);
    }
    if (lane < Ee) {
        double m = acc[0];
#pragma unroll
        for (int e = 1; e < Ee; ++e) m = acc[e] > m ? acc[e] : m;
        double sum = 0.0;
#pragma unroll
        for (int e = 0; e < Ee; ++e) sum += exp(acc[e] - m);
        double v = exp(acc[lane] - m) / sum;
        Sm[((size_t)(b * Ee + lane)) * Ss + s] = (float)v;
    }
}

// ---------------------------------------------------------------------------
// 2) Top-K per (b,e): bitonic sort of 2048 keys; ties -> lower index first
// ---------------------------------------------------------------------------
__global__ __launch_bounds__(1024) void topk_kernel(
    const float* __restrict__ Sm, int* __restrict__ I, float* __restrict__ G)
{
    __shared__ unsigned long long keys[Ss];
    int be = blockIdx.x;
    const float* row = Sm + (size_t)be * Ss;
    for (int i = threadIdx.x; i < Ss; i += 1024) {
        unsigned int vb = __float_as_uint(row[i]);
        keys[i] = ((unsigned long long)vb << 32) | (unsigned int)(0xFFFFFFFFu - i);
    }
    __syncthreads();
    for (int k = 2; k <= Ss; k <<= 1) {
        for (int j = k >> 1; j > 0; j >>= 1) {
            for (int i = threadIdx.x; i < Ss; i += 1024) {
                int ixj = i ^ j;
                if (ixj > i) {
                    unsigned long long a = keys[i], c = keys[ixj];
                    bool desc = ((i & k) == 0);
                    if (desc ? (a < c) : (a > c)) { keys[i] = c; keys[ixj] = a; }
                }
            }
            __syncthreads();
        }
    }
    if (threadIdx.x < Kk) {
        unsigned long long kk = keys[threadIdx.x];
        I[(size_t)be * Kk + threadIdx.x] = (int)(0xFFFFFFFFu - (unsigned int)(kk & 0xFFFFFFFFu));
        G[(size_t)be * Kk + threadIdx.x] = __uint_as_float((unsigned int)(kk >> 32));
    }
}

// ---------------------------------------------------------------------------
// 2b) Inverse index: for each (b,token) the list of slots (e*K+k) that chose
//     it. Expert-choice guarantees <= 1 slot per expert -> <= Ee entries.
// ---------------------------------------------------------------------------
__global__ __launch_bounds__(256) void inv_build_kernel(
    const int* __restrict__ I, int* __restrict__ cnt, int* __restrict__ inv)
{
    int slot = blockIdx.x * 256 + threadIdx.x;      // [B*E*K)
    int b = slot / (Ee * Kk);
    int sid = slot - b * (Ee * Kk);                 // e*Kk + k
    int t = I[slot];
    int p = atomicAdd(&cnt[b * Ss + t], 1);
    inv[(size_t)(b * Ss + t) * Ee + p] = sid;
}

// ---------------------------------------------------------------------------
// 2c) Combine: out[b,t,:] = sum over listed slots of Oe[bl*E*K + sid, :].
//     One 256-thread block per token, float4 per lane. Writes EVERY token
//     (zeros if cnt==0) -> no out memset needed.
// ---------------------------------------------------------------------------
__global__ __launch_bounds__(256) void combine_kernel(
    const float4* __restrict__ Oe, const int* __restrict__ cnt,
    const int* __restrict__ inv, float4* __restrict__ out, int b0)
{
    int blk = blockIdx.x;                 // bl*Ss + s
    int bl = blk >> 11, s = blk & (Ss - 1);
    int tok = (b0 + bl) * Ss + s;
    int tid = threadIdx.x;                // col4 index (Hh/4 = 256)
    int c = cnt[tok];
    const int* lst = inv + (size_t)tok * Ee;
    float4 acc = {0.f, 0.f, 0.f, 0.f};
    for (int i = 0; i < c; ++i) {
        int sid = lst[i];
        float4 v = Oe[((size_t)bl * (Ee * Kk) + sid) * (Hh / 4) + tid];
        acc.x += v.x; acc.y += v.y; acc.z += v.z; acc.w += v.w;
    }
    out[(size_t)tok * (Hh / 4) + tid] = acc;
}

// ---------------------------------------------------------------------------
// 3) Transpose + cast fp32 -> bf16, 128x128 tiles.
//    dst[z][c][r] = bf16(src[z][r][c])  (see r2 notes: packed bf16 row-pairs)
// ---------------------------------------------------------------------------
__global__ __launch_bounds__(256) void transpose_cast_kernel(
    const float* __restrict__ src, unsigned short* __restrict__ dst, int R, int C)
{
    __shared__ unsigned int tileT[128 * 65];   // 33 KB, 4 blocks/CU
    int z = blockIdx.z;
    const float* s = src + (size_t)z * R * C;
    unsigned short* d = dst + (size_t)z * R * C;
    int c0 = blockIdx.x * 128, r0 = blockIdx.y * 128;
    int t = threadIdx.x;

    int cq = t & 31;            // 16B column chunk within a row
    int rp0 = t >> 5;           // row-pair base (0..7)
#pragma unroll
    for (int p = 0; p < 8; ++p) {
        int rp = rp0 + p * 8;   // 0..63
        const float* s0 = s + (size_t)(r0 + 2 * rp) * C + c0 + cq * 4;
        float4 a = *(const float4*)s0;
        float4 b = *(const float4*)(s0 + C);
        const float* af = (const float*)&a;
        const float* bf = (const float*)&b;
#pragma unroll
        for (int i = 0; i < 4; ++i) {
            unsigned int lo = f2bf(af[i]);
            unsigned int hi = f2bf(bf[i]);
            tileT[(cq * 4 + i) * 65 + rp] = lo | (hi << 16);
        }
    }
    __syncthreads();

    int cw0 = t >> 4;           // column base (0..15), +16 per pass
    int rseg = t & 15;          // 16B r-chunk (8 elems)
#pragma unroll
    for (int p = 0; p < 8; ++p) {
        int c = cw0 + p * 16;
        u16x8 o;
#pragma unroll
        for (int k = 0; k < 4; ++k) {
            unsigned int dd = tileT[c * 65 + rseg * 4 + k];
            o[2 * k]     = (unsigned short)(dd & 0xFFFFu);
            o[2 * k + 1] = (unsigned short)(dd >> 16);
        }
        *(u16x8*)(d + (size_t)(c0 + c) * R + r0 + rseg * 8) = o;
    }
}

// ---------------------------------------------------------------------------
// GEMM: 256x256 tile, BK=64, 512 threads = 8 waves (2M x 4N), 8-phase
// software-pipelined K-loop (m201 template) — see r1 notes. Schedule
// unchanged since r1 (verified); only epilogues differ per kernel.
// ---------------------------------------------------------------------------

#define BAR { asm volatile("" ::: "memory"); __builtin_amdgcn_s_barrier(); asm volatile("" ::: "memory"); }
#define VMW6 asm volatile("s_waitcnt vmcnt(6)" ::: "memory");
#define VMW8 asm volatile("s_waitcnt vmcnt(8)" ::: "memory");
#define PRIO1 __builtin_amdgcn_s_setprio(1);
#define PRIO0 __builtin_amdgcn_s_setprio(0);

#define RD_A(bufi, h) { \
    _Pragma("unroll") for (int i = 0; i < 4; ++i) \
    _Pragma("unroll") for (int ks = 0; ks < 2; ++ks) \
        a[i][ks] = *(const bf16x8*)(ldsc + (bufi)*65536 + (h)*16384 \
            + ((wm64 + i*16 + fr) << 7) + (((ks*4 + quad) ^ fr7) << 4)); }

#define RD_B(bufi, h, B) { \
    _Pragma("unroll") for (int j = 0; j < 2; ++j) \
    _Pragma("unroll") for (int ks = 0; ks < 2; ++ks) \
        B[j][ks] = *(const bf16x8*)(ldsc + (bufi)*65536 + 32768 + (h)*16384 \
            + ((wn32 + j*16 + fr) << 7) + (((ks*4 + quad) ^ fr7) << 4)); }

#define STG_A(bufi, h, kt) { \
    char* _d = ldsm + (bufi)*65536 + (h)*16384 + stoff; \
    async_copy16(srcA[(h)*2+0] + (size_t)(kt)*64, _d); \
    async_copy16(srcA[(h)*2+1] + (size_t)(kt)*64, _d + 1024); }

#define STG_B(bufi, h, kt) { \
    char* _d = ldsm + (bufi)*65536 + 32768 + (h)*16384 + stoff; \
    async_copy16(srcB[(h)*2+0] + (size_t)(kt)*64, _d); \
    async_copy16(srcB[(h)*2+1] + (size_t)(kt)*64, _d + 1024); }

#define MFMA_Q(q, c, B) { \
    _Pragma("unroll") for (int i = 0; i < 4; ++i) \
    _Pragma("unroll") for (int j = 0; j < 2; ++j) \
    _Pragma("unroll") for (int ks = 0; ks < 2; ++ks) \
        acc[q][c][i][j] = __builtin_amdgcn_mfma_f32_16x16x32_bf16( \
            a[i][ks], B[j][ks], acc[q][c][i][j], 0, 0, 0); }

#define GEMM_MAIN(NTILES) \
    f32x4 acc[2][2][4][2] = {}; \
    bf16x8 a[4][2], br0[2][2], br1[2][2]; \
    STG_B(0,0,0) STG_A(0,0,0) STG_B(0,1,0) STG_A(0,1,0) \
    STG_B(1,0,1) STG_A(1,0,1) STG_B(1,1,1) STG_A(1,1,1) \
    VMW8 BAR \
    RD_B(0,0,br0) \
    for (int t2 = 0; t2 < (NTILES); t2 += 2) { \
        const int ka = (t2 + 2 < (NTILES)) ? t2 + 2 : 0; \
        const int kb = (t2 + 3 < (NTILES)) ? t2 + 3 : 0; \
        RD_A(0,0)      STG_B(0,0,ka)      BAR PRIO1 MFMA_Q(0,0,br0) PRIO0 BAR \
        RD_B(0,1,br1)  STG_A(0,0,ka)      BAR PRIO1 MFMA_Q(0,1,br1) PRIO0 BAR \
        RD_A(0,1)      STG_B(0,1,ka) VMW6 BAR PRIO1 MFMA_Q(1,0,br0) PRIO0 BAR \
        RD_B(1,0,br0)  STG_A(0,1,ka)      BAR PRIO1 MFMA_Q(1,1,br1) PRIO0 BAR \
        RD_A(1,0)      STG_B(1,0,kb)      BAR PRIO1 MFMA_Q(0,0,br0) PRIO0 BAR \
        RD_B(1,1,br1)  STG_A(1,0,kb)      BAR PRIO1 MFMA_Q(0,1,br1) PRIO0 BAR \
        RD_A(1,1)      STG_B(1,1,kb) VMW6 BAR PRIO1 MFMA_Q(1,0,br0) PRIO0 BAR \
        RD_B(0,0,br0)  STG_A(1,1,kb)      BAR PRIO1 MFMA_Q(1,1,br1) PRIO0 BAR \
    }

// common per-thread geometry + bijective XCD-chunk swizzle (grid % 8 == 0)
#define GEMM_PREAMBLE \
    const int t = threadIdx.x; \
    const int lane = t & 63, w = t >> 6; \
    const int wm64 = (w >> 2) * 64, wn32 = (w & 3) * 32; \
    const int fr = lane & 15, quad = lane >> 4, fr7 = lane & 7; \
    const int l3 = lane >> 3; \
    const int sc = ((lane & 7) ^ l3) * 8; \
    const int stoff = w * 2048; \
    const int nx = gridDim.x, ny = gridDim.y; \
    const int nwg = nx * ny * gridDim.z; \
    const int flat = blockIdx.x + nx * (blockIdx.y + ny * blockIdx.z); \
    const int lid = (flat & 7) * (nwg >> 3) + (flat >> 3); \
    const int tn = lid % nx; \
    const int _rest = lid / nx; \
    const int by = _rest % ny; \
    const int e = _rest / ny; \
    const int bl = by >> 1, tm = by & 1; \
    const int b = b0 + bl; \
    __shared__ __align__(128) char lds[131072]; \
    const char* ldsc = lds; char* ldsm = lds;

__global__ __launch_bounds__(512, 2) void gemm1_kernel(
    const unsigned short* __restrict__ xb,   // [B,S,H] bf16
    const unsigned short* __restrict__ w1t,  // [E,F,H] bf16
    const float* __restrict__ b1, const int* __restrict__ I,
    unsigned short* __restrict__ h1,         // [gb,E,K,F] bf16
    int b0)
{
    GEMM_PREAMBLE
    const int ib = (b * Ee + e) * Kk + tm * 256;
    const unsigned short* srcA[4];
    const unsigned short* srcB[4];
#pragma unroll
    for (int h = 0; h < 2; ++h)
#pragma unroll
        for (int inst = 0; inst < 2; ++inst) {
            int r = h * 128 + w * 16 + inst * 8 + l3;
            srcA[h * 2 + inst] = xb + ((size_t)(b * Ss + I[ib + r])) * Hh + sc;
            srcB[h * 2 + inst] = w1t + ((size_t)e * Ff + tn * 256 + r) * Hh + sc;
        }

    GEMM_MAIN(Hh / 64)

    float bias[2][2];
#pragma unroll
    for (int c = 0; c < 2; ++c)
#pragma unroll
        for (int j = 0; j < 2; ++j)
            bias[c][j] = b1[(size_t)e * Ff + tn * 256 + c * 128 + wn32 + j * 16 + fr];
#pragma unroll
    for (int q = 0; q < 2; ++q)
#pragma unroll
        for (int i = 0; i < 4; ++i)
#pragma unroll
            for (int r = 0; r < 4; ++r) {
                int m = tm * 256 + q * 128 + wm64 + i * 16 + quad * 4 + r;
                unsigned short* orow = h1 + (((size_t)bl * Ee + e) * Kk + m) * Ff + tn * 256;
#pragma unroll
                for (int c = 0; c < 2; ++c)
#pragma unroll
                    for (int j = 0; j < 2; ++j)
                        orow[c * 128 + wn32 + j * 16 + fr] =
                            f2bf(gelu(acc[q][c][i][j][r] + bias[c][j]));
            }
}

__global__ __launch_bounds__(512, 2) void gemm2_kernel(
    const unsigned short* __restrict__ h1,   // [gb,E,K,F] bf16
    const unsigned short* __restrict__ w2t,  // [E,H,F] bf16
    const float* __restrict__ b2, const float* __restrict__ G,
    float* __restrict__ Oe,                  // [gb*E*K, H] fp32, gated
    int b0)
{
    GEMM_PREAMBLE
    const unsigned short* srcA[4];
    const unsigned short* srcB[4];
#pragma unroll
    for (int h = 0; h < 2; ++h)
#pragma unroll
        for (int inst = 0; inst < 2; ++inst) {
            int r = h * 128 + w * 16 + inst * 8 + l3;
            srcA[h * 2 + inst] = h1 + (((size_t)bl * Ee + e) * Kk + tm * 256 + r) * Ff + sc;
            srcB[h * 2 + inst] = w2t + ((size_t)e * Hh + tn * 256 + r) * Ff + sc;
        }

    GEMM_MAIN(Ff / 64)

    float bias[2][2];
#pragma unroll
    for (int c = 0; c < 2; ++c)
#pragma unroll
        for (int j = 0; j < 2; ++j)
            bias[c][j] = b2[(size_t)e * Hh + tn * 256 + c * 128 + wn32 + j * 16 + fr];
#pragma unroll
    for (int q = 0; q < 2; ++q)
#pragma unroll
        for (int i = 0; i < 4; ++i)
#pragma unroll
            for (int r = 0; r < 4; ++r) {
                int m = tm * 256 + q * 128 + wm64 + i * 16 + quad * 4 + r;
                int slot = (b * Ee + e) * Kk + m;
                float gate = G[slot];
                float* orow = Oe + (((size_t)bl * Ee + e) * Kk + m) * Hh + tn * 256;
#pragma unroll
                for (int c = 0; c < 2; ++c)
#pragma unroll
                    for (int j = 0; j < 2; ++j)
                        orow[c * 128 + wn32 + j * 16 + fr] =
                            (acc[q][c][i][j][r] + bias[c][j]) * gate;
            }
}

// ---------------------------------------------------------------------------
extern "C" void kernel_launch(void* const* d_in, const int* in_sizes, int n_in,
                              void* d_out, int out_size, void* d_ws, size_t ws_size,
                              hipStream_t stream) {
    const float* x  = (const float*)d_in[0];   // [B,S,H]
    const float* Wg = (const float*)d_in[1];   // [E,H]
    const float* W1 = (const float*)d_in[2];   // [E,H,F]
    const float* b1 = (const float*)d_in[3];   // [E,F]
    const float* W2 = (const float*)d_in[4];   // [E,F,H]
    const float* b2 = (const float*)d_in[5];   // [E,H]
    float* out = (float*)d_out;                // [B,S,H]

    size_t off = 0;
    char* base = (char*)d_ws;
    auto alloc = [&](size_t bytes) -> void* {
        void* p = base + off;
        off += (bytes + 255) & ~(size_t)255;
        return p;
    };
    float* Sm  = (float*)alloc((size_t)Bb * Ee * Ss * 4);
    int*   I   = (int*)alloc((size_t)Bb * Ee * Kk * 4);
    float* G   = (float*)alloc((size_t)Bb * Ee * Kk * 4);
    int*   cnt = (int*)alloc((size_t)Bb * Ss * 4);              // 32 KB
    int*   inv = (int*)alloc((size_t)Bb * Ss * Ee * 4);         // 256 KB
    unsigned short* W2T = (unsigned short*)alloc((size_t)Ee * Hh * Ff * 2); // [E,H,F]
    // keep W1T and xb ADJACENT: after the (single, gb=4) gemm1 dispatch both
    // are dead, and their 80 MB window hosts Oe (67.1 MB) via aliasing.
    unsigned short* W1T = (unsigned short*)alloc((size_t)Ee * Ff * Hh * 2); // [E,F,H]
    unsigned short* xb  = (unsigned short*)alloc((size_t)Bb * Ss * Hh * 2); // [B,S,H]
    size_t fixed = off;
    size_t h1_per_b = (size_t)Ee * Kk * Ff * 2;   // 32 MiB
    size_t oe_per_b = (size_t)Ee * Kk * Hh * 4;   // 16.8 MiB
    int gb;
    unsigned short* h1;
    float* Oe;
    if (fixed + 4 * h1_per_b <= ws_size) {
        gb = 4;
        h1 = (unsigned short*)alloc(4 * h1_per_b);
        Oe = (float*)W1T;                          // alias: W1T+xb window (80 MB)
    } else {
        gb = 2;
        while (gb > 1 && fixed + (size_t)gb * (h1_per_b + oe_per_b) > ws_size) gb >>= 1;
        h1 = (unsigned short*)alloc((size_t)gb * h1_per_b);
        Oe = (float*)alloc((size_t)gb * oe_per_b);
        if (off > ws_size) return;
    }

    hipMemsetAsync(cnt, 0, (size_t)Bb * Ss * 4, stream);

    cast_kernel<<<(Bb * Ss * Hh) / 1024, 256, 0, stream>>>((const float4*)x, (ushort4*)xb);
    gating_kernel<<<(Bb * Ss) / 4, 256, 0, stream>>>(x, Wg, Sm);
    topk_kernel<<<Bb * Ee, 1024, 0, stream>>>(Sm, I, G);
    inv_build_kernel<<<(Bb * Ee * Kk) / 256, 256, 0, stream>>>(I, cnt, inv);
    transpose_cast_kernel<<<dim3(Ff / 128, Hh / 128, Ee), 256, 0, stream>>>(W1, W1T, Hh, Ff);
    transpose_cast_kernel<<<dim3(Hh / 128, Ff / 128, Ee), 256, 0, stream>>>(W2, W2T, Ff, Hh);

    for (int g = 0; g < Bb / gb; ++g) {
        gemm1_kernel<<<dim3(Ff / 256, 2 * gb, Ee), 512, 0, stream>>>(xb, W1T, b1, I, h1, g * gb);
        gemm2_kernel<<<dim3(Hh / 256, 2 * gb, Ee), 512, 0, stream>>>(h1, W2T, b2, G, Oe, g * gb);
        combine_kernel<<<gb * Ss, 256, 0, stream>>>((const float4*)Oe, cnt, inv,
                                                    (float4*)out, g * gb);
    }
}